// Round 8
// baseline (590.690 us; speedup 1.0000x reference)
//
#include <hip/hip_runtime.h>
#include <hip/hip_bf16.h>
#include <math.h>

#define N_NODES 20000
#define F 128
#define NRBF 20
#define E_EDGES 320000
#define F3 (3 * F)   // 384
#define NCHUNK ((N_NODES + 255) / 256)   // 79

typedef __attribute__((ext_vector_type(8))) short bf16x8;
typedef __attribute__((ext_vector_type(4))) float f32x4;

__device__ __forceinline__ float silu_f(float x) {
    return x / (1.0f + __expf(-x));
}
__device__ __forceinline__ unsigned short bf_bits(float x) {
    __hip_bfloat16 b = __float2bfloat16(x);
    return *(unsigned short*)&b;
}

// ---------------------------------------------------------------------------
// Weight pre-swizzle into MFMA B-fragment order (unchanged from R7).
// ---------------------------------------------------------------------------
__global__ __launch_bounds__(256) void w_swizzle_kernel(
    const float* __restrict__ W1, const float* __restrict__ W2,
    unsigned short* __restrict__ W1s, unsigned short* __restrict__ W2s)
{
    int tid = blockIdx.x * 256 + threadIdx.x;
    if (tid < 8 * 4 * 64) {
        int lane = tid & 63, kc = (tid >> 6) & 3, ct = tid >> 8;
        int n = ct * 16 + (lane & 15);
        int k0 = kc * 32 + (lane >> 4) * 8;
        #pragma unroll
        for (int j = 0; j < 8; ++j)
            W1s[tid * 8 + j] = bf_bits(W1[(k0 + j) * F + n]);
    } else if (tid < 8 * 4 * 64 + 24 * 4 * 64) {
        int t = tid - 8 * 4 * 64;
        int lane = t & 63, kc = (t >> 6) & 3, ct = t >> 8;
        int n = ct * 16 + (lane & 15);
        int k0 = kc * 32 + (lane >> 4) * 8;
        #pragma unroll
        for (int j = 0; j < 8; ++j)
            W2s[t * 8 + j] = bf_bits(W2[(k0 + j) * F3 + n]);
    }
}

// ---------------------------------------------------------------------------
// Kernel A (MFMA): h = silu(s@W1+b1)@W2 + b2 (unchanged from R7).
// ---------------------------------------------------------------------------
#define SLD 136
__global__ __launch_bounds__(256) void node_mlp_mfma(
    const float* __restrict__ s, const float* __restrict__ b1,
    const float* __restrict__ b2,
    const unsigned short* __restrict__ W1s, const unsigned short* __restrict__ W2s,
    float* __restrict__ h)
{
    __shared__ unsigned short Sl[64][SLD];
    __shared__ unsigned short Hid[4][16][SLD];

    const int tid = threadIdx.x;
    const int lane = tid & 63, wave = tid >> 6;
    const int m = lane & 15, quad = lane >> 4;
    const int n0 = blockIdx.x * 64;

    for (int i = tid; i < 64 * F; i += 256) {
        int r = i >> 7, c = i & 127;
        int nn = n0 + r;
        if (nn >= N_NODES) nn = N_NODES - 1;
        Sl[r][c] = bf_bits(s[(size_t)nn * F + c]);
    }
    __syncthreads();

    const int arow = wave * 16 + m;
    bf16x8 a1[4];
    #pragma unroll
    for (int kc = 0; kc < 4; ++kc)
        a1[kc] = *(const bf16x8*)&Sl[arow][kc * 32 + quad * 8];

    const bf16x8* W1f = (const bf16x8*)W1s;
    #pragma unroll
    for (int ct = 0; ct < 8; ++ct) {
        f32x4 acc = {0.f, 0.f, 0.f, 0.f};
        #pragma unroll
        for (int kc = 0; kc < 4; ++kc)
            acc = __builtin_amdgcn_mfma_f32_16x16x32_bf16(
                a1[kc], W1f[(ct * 4 + kc) * 64 + lane], acc, 0, 0, 0);
        float bias = b1[ct * 16 + m];
        #pragma unroll
        for (int r = 0; r < 4; ++r)
            Hid[wave][quad * 4 + r][ct * 16 + m] = bf_bits(silu_f(acc[r] + bias));
    }
    __syncthreads();

    bf16x8 a2[4];
    #pragma unroll
    for (int kc = 0; kc < 4; ++kc)
        a2[kc] = *(const bf16x8*)&Hid[wave][m][kc * 32 + quad * 8];

    const bf16x8* W2f = (const bf16x8*)W2s;
    #pragma unroll
    for (int ct = 0; ct < 24; ++ct) {
        f32x4 acc = {0.f, 0.f, 0.f, 0.f};
        #pragma unroll
        for (int kc = 0; kc < 4; ++kc)
            acc = __builtin_amdgcn_mfma_f32_16x16x32_bf16(
                a2[kc], W2f[(ct * 4 + kc) * 64 + lane], acc, 0, 0, 0);
        float bias = b2[ct * 16 + m];
        #pragma unroll
        for (int r = 0; r < 4; ++r) {
            int node = n0 + wave * 16 + quad * 4 + r;
            if (node < N_NODES)
                h[(size_t)node * F3 + ct * 16 + m] = acc[r] + bias;
        }
    }
}

// ---------------------------------------------------------------------------
// CSR build (unchanged)
// ---------------------------------------------------------------------------
__global__ __launch_bounds__(256) void hist_kernel(const int* __restrict__ i_index,
                                                   int* __restrict__ counts)
{
    int e = blockIdx.x * 256 + threadIdx.x;
    if (e < E_EDGES) atomicAdd(&counts[i_index[e]], 1);
}

__global__ __launch_bounds__(256) void scan_p1(const int* __restrict__ counts,
                                               int* __restrict__ row_start,
                                               int* __restrict__ chunk_sum)
{
    __shared__ int buf[256];
    const int tid = threadIdx.x;
    const int idx = blockIdx.x * 256 + tid;
    int val = (idx < N_NODES) ? counts[idx] : 0;
    buf[tid] = val;
    __syncthreads();
    for (int off = 1; off < 256; off <<= 1) {
        int t = (tid >= off) ? buf[tid - off] : 0;
        __syncthreads();
        buf[tid] += t;
        __syncthreads();
    }
    if (idx < N_NODES) row_start[idx] = buf[tid] - val;
    if (tid == 255) chunk_sum[blockIdx.x] = buf[255];
}

__global__ __launch_bounds__(128) void scan_p2(const int* __restrict__ chunk_sum,
                                               int* __restrict__ chunk_off)
{
    __shared__ int buf[128];
    const int tid = threadIdx.x;
    int val = (tid < NCHUNK) ? chunk_sum[tid] : 0;
    buf[tid] = val;
    __syncthreads();
    for (int off = 1; off < 128; off <<= 1) {
        int t = (tid >= off) ? buf[tid - off] : 0;
        __syncthreads();
        buf[tid] += t;
        __syncthreads();
    }
    if (tid < NCHUNK) chunk_off[tid] = buf[tid] - val;
}

__global__ __launch_bounds__(256) void scan_p3(int* __restrict__ row_start,
                                               const int* __restrict__ chunk_off,
                                               int* __restrict__ cursor)
{
    int idx = blockIdx.x * 256 + threadIdx.x;
    if (idx < N_NODES) {
        int vv = row_start[idx] + chunk_off[blockIdx.x];
        row_start[idx] = vv;
        cursor[idx] = vv;
    }
    if (idx == 0) row_start[N_NODES] = E_EDGES;
}

__global__ __launch_bounds__(256) void scatter_kernel(const int* __restrict__ i_index,
                                                      int* __restrict__ cursor,
                                                      int* __restrict__ edge_ids)
{
    int e = blockIdx.x * 256 + threadIdx.x;
    if (e < E_EDGES) {
        int pos = atomicAdd(&cursor[i_index[e]], 1);
        edge_ids[pos] = e;
    }
}

// ---------------------------------------------------------------------------
// Kernel B: aggregation. 256 threads = 2 independent nodes per block
// (half = tid>>7). Per-thread body identical to the proven R2 form, plus
// next-edge index prefetch to overlap the e->j load chain with compute.
// ---------------------------------------------------------------------------
__global__ __launch_bounds__(256) void agg_kernel(
    const float* __restrict__ s, const float* __restrict__ v,
    const float* __restrict__ rbf, const float* __restrict__ dir,
    const int* __restrict__ j_index,
    const float* __restrict__ Wr, const float* __restrict__ br,
    const float* __restrict__ h,
    const int* __restrict__ row_start, const int* __restrict__ edge_ids,
    float* __restrict__ s_agg, float* __restrict__ v_agg)
{
    const int f = threadIdx.x & 127;
    const int n = blockIdx.x * 2 + (threadIdx.x >> 7);

    float wr0[NRBF], wr1[NRBF], wr2[NRBF];
    #pragma unroll
    for (int k = 0; k < NRBF; ++k) {
        wr0[k] = Wr[k * F3 + f];
        wr1[k] = Wr[k * F3 + F + f];
        wr2[k] = Wr[k * F3 + 2 * F + f];
    }
    const float br0 = br[f], br1 = br[F + f], br2 = br[2 * F + f];

    float s_acc = s[(size_t)n * F + f];
    float v0 = v[(size_t)n * F3 + f * 3 + 0];
    float v1 = v[(size_t)n * F3 + f * 3 + 1];
    float v2 = v[(size_t)n * F3 + f * 3 + 2];

    const int beg = row_start[n];
    const int end = row_start[n + 1];
    const float cc = 0.6283185307179586f;   // pi/5

    if (beg < end) {
        int e = edge_ids[beg];
        int j = j_index[e];
        for (int idx = beg; idx < end; ++idx) {
            // prefetch next edge's indices so their latency overlaps this
            // edge's gathers + filter math
            int e_nxt = e, j_nxt = j;
            if (idx + 1 < end) {
                e_nxt = edge_ids[idx + 1];
                j_nxt = j_index[e_nxt];
            }

            float x0 = br0, x1 = br1, x2 = br2;
            #pragma unroll
            for (int k = 0; k < NRBF; ++k) {
                float r = rbf[(size_t)e * NRBF + k];
                x0 += r * wr0[k];
                x1 += r * wr1[k];
                x2 += r * wr2[k];
            }
            float w0 = (x0 < 5.0f) ? 0.5f * (__cosf(x0 * cc) + 1.0f) : 0.0f;
            float w1 = (x1 < 5.0f) ? 0.5f * (__cosf(x1 * cc) + 1.0f) : 0.0f;
            float w2 = (x2 < 5.0f) ? 0.5f * (__cosf(x2 * cc) + 1.0f) : 0.0f;

            float hs  = h[(size_t)j * F3 + f]         * w0;
            float hvs = h[(size_t)j * F3 + F + f]     * w1;
            float hvv = h[(size_t)j * F3 + 2 * F + f] * w2;

            float dx = dir[(size_t)e * 3 + 0];
            float dy = dir[(size_t)e * 3 + 1];
            float dz = dir[(size_t)e * 3 + 2];

            float vj0 = v[(size_t)j * F3 + f * 3 + 0];
            float vj1 = v[(size_t)j * F3 + f * 3 + 1];
            float vj2 = v[(size_t)j * F3 + f * 3 + 2];

            s_acc += hs;
            v0 += hvs * dx + hvv * vj0;
            v1 += hvs * dy + hvv * vj1;
            v2 += hvs * dz + hvv * vj2;

            e = e_nxt; j = j_nxt;
        }
    }

    s_agg[(size_t)n * F + f] = s_acc;
    v_agg[(size_t)n * F3 + f * 3 + 0] = v0;
    v_agg[(size_t)n * F3 + f * 3 + 1] = v1;
    v_agg[(size_t)n * F3 + f * 3 + 2] = v2;
}

// ---------------------------------------------------------------------------
// Kernel C: per-node update. 256 threads = two independent T_C=4 halves;
// per-thread code identical to the proven R2 form.
// ---------------------------------------------------------------------------
#define T_C 4
__global__ __launch_bounds__(256) void update_kernel(
    const float* __restrict__ s_agg, const float* __restrict__ v_agg,
    const float* __restrict__ WU, const float* __restrict__ bU,
    const float* __restrict__ WV, const float* __restrict__ bV,
    const float* __restrict__ M1, const float* __restrict__ bm1,
    const float* __restrict__ M2, const float* __restrict__ bm2,
    float* __restrict__ s_out, float* __restrict__ v_out)
{
    __shared__ float vl[2][T_C][F][3];
    __shared__ float inl[2][T_C][2 * F];
    __shared__ float hidl[2][T_C][F];

    const int g = threadIdx.x & 127;
    const int half = threadIdx.x >> 7;
    const int n0 = blockIdx.x * 2 * T_C + half * T_C;

    for (int idx = g; idx < T_C * F3; idx += 128)
        ((float*)vl[half])[idx] = v_agg[(size_t)n0 * F3 + idx];
    #pragma unroll
    for (int t = 0; t < T_C; ++t)
        inl[half][t][F + g] = s_agg[(size_t)(n0 + t) * F + g];
    __syncthreads();

    float uacc[T_C][3], vacc[T_C][3];
    #pragma unroll
    for (int t = 0; t < T_C; ++t)
        #pragma unroll
        for (int d = 0; d < 3; ++d) { uacc[t][d] = 0.0f; vacc[t][d] = 0.0f; }

    for (int f = 0; f < F; ++f) {
        float wu = WU[f * F + g];
        float wv = WV[f * F + g];
        #pragma unroll
        for (int t = 0; t < T_C; ++t) {
            #pragma unroll
            for (int d = 0; d < 3; ++d) {
                float vv = vl[half][t][f][d];
                uacc[t][d] += vv * wu;
                vacc[t][d] += vv * wv;
            }
        }
    }
    float bu = bU[g], bv = bV[g];
    #pragma unroll
    for (int t = 0; t < T_C; ++t) {
        #pragma unroll
        for (int d = 0; d < 3; ++d) { uacc[t][d] += bu; vacc[t][d] += bv; }
        inl[half][t][g] = sqrtf(vacc[t][0] * vacc[t][0] + vacc[t][1] * vacc[t][1] +
                                vacc[t][2] * vacc[t][2]);
    }
    __syncthreads();

    float hacc[T_C];
    #pragma unroll
    for (int t = 0; t < T_C; ++t) hacc[t] = 0.0f;
    for (int k = 0; k < 2 * F; ++k) {
        float m1 = M1[k * F + g];
        #pragma unroll
        for (int t = 0; t < T_C; ++t) hacc[t] += inl[half][t][k] * m1;
    }
    float bh = bm1[g];
    #pragma unroll
    for (int t = 0; t < T_C; ++t) hidl[half][t][g] = silu_f(hacc[t] + bh);
    __syncthreads();

    float macc[3][T_C];
    #pragma unroll
    for (int o3 = 0; o3 < 3; ++o3)
        #pragma unroll
        for (int t = 0; t < T_C; ++t) macc[o3][t] = 0.0f;
    for (int k = 0; k < F; ++k) {
        #pragma unroll
        for (int o3 = 0; o3 < 3; ++o3) {
            float m2 = M2[k * F3 + o3 * F + g];
            #pragma unroll
            for (int t = 0; t < T_C; ++t) macc[o3][t] += hidl[half][t][k] * m2;
        }
    }
    const float bvv = bm2[g], bsv = bm2[F + g], bss = bm2[2 * F + g];

    #pragma unroll
    for (int t = 0; t < T_C; ++t) {
        float a_vv = macc[0][t] + bvv;
        float a_sv = macc[1][t] + bsv;
        float a_ss = macc[2][t] + bss;
        float dotuv = uacc[t][0] * vacc[t][0] + uacc[t][1] * vacc[t][1] +
                      uacc[t][2] * vacc[t][2];
        s_out[(size_t)(n0 + t) * F + g] = inl[half][t][F + g] + dotuv * a_sv + a_ss;
        #pragma unroll
        for (int d = 0; d < 3; ++d)
            v_out[(size_t)(n0 + t) * F3 + g * 3 + d] = vl[half][t][g][d] + a_vv * uacc[t][d];
    }
}

// ---------------------------------------------------------------------------
extern "C" void kernel_launch(void* const* d_in, const int* in_sizes, int n_in,
                              void* d_out, int out_size, void* d_ws, size_t ws_size,
                              hipStream_t stream) {
    const float* s    = (const float*)d_in[0];
    const float* v    = (const float*)d_in[1];
    const float* rbf  = (const float*)d_in[2];
    const float* dir  = (const float*)d_in[3];
    const float* W1   = (const float*)d_in[4];
    const float* b1   = (const float*)d_in[5];
    const float* W2   = (const float*)d_in[6];
    const float* b2   = (const float*)d_in[7];
    const float* Wr   = (const float*)d_in[8];
    const float* br   = (const float*)d_in[9];
    const float* WU   = (const float*)d_in[10];
    const float* bU   = (const float*)d_in[11];
    const float* WV   = (const float*)d_in[12];
    const float* bV   = (const float*)d_in[13];
    const float* M1   = (const float*)d_in[14];
    const float* bm1  = (const float*)d_in[15];
    const float* M2   = (const float*)d_in[16];
    const float* bm2  = (const float*)d_in[17];
    const int* i_index = (const int*)d_in[18];
    const int* j_index = (const int*)d_in[19];

    float* out_s = (float*)d_out;                     // N*F
    float* out_v = out_s + (size_t)N_NODES * F;       // N*F*3

    // workspace layout
    float* h       = (float*)d_ws;                         // N*384 floats
    float* s_agg   = h + (size_t)N_NODES * F3;             // N*128
    float* v_agg   = s_agg + (size_t)N_NODES * F;          // N*384
    int*   counts  = (int*)(v_agg + (size_t)N_NODES * F3); // N
    int*   row_start = counts + N_NODES;                   // N+1
    int*   cursor  = row_start + N_NODES + 1;              // N
    int*   edge_ids = cursor + N_NODES;                    // E
    int*   chunk_sum = edge_ids + E_EDGES;                 // 128
    int*   chunk_off = chunk_sum + 128;                    // 128
    unsigned short* W1s = (unsigned short*)(chunk_off + 128);  // 8*4*64*8
    unsigned short* W2s = W1s + 8 * 4 * 64 * 8;                // 24*4*64*8

    hipMemsetAsync(counts, 0, sizeof(int) * N_NODES, stream);

    w_swizzle_kernel<<<32, 256, 0, stream>>>(W1, W2, W1s, W2s);
    node_mlp_mfma<<<(N_NODES + 63) / 64, 256, 0, stream>>>(s, b1, b2, W1s, W2s, h);

    hist_kernel<<<(E_EDGES + 255) / 256, 256, 0, stream>>>(i_index, counts);
    scan_p1<<<NCHUNK, 256, 0, stream>>>(counts, row_start, chunk_sum);
    scan_p2<<<1, 128, 0, stream>>>(chunk_sum, chunk_off);
    scan_p3<<<NCHUNK, 256, 0, stream>>>(row_start, chunk_off, cursor);
    scatter_kernel<<<(E_EDGES + 255) / 256, 256, 0, stream>>>(i_index, cursor, edge_ids);

    agg_kernel<<<N_NODES / 2, 256, 0, stream>>>(s, v, rbf, dir, j_index, Wr, br, h,
                                                row_start, edge_ids, s_agg, v_agg);

    update_kernel<<<N_NODES / (2 * T_C), 256, 0, stream>>>(s_agg, v_agg, WU, bU, WV, bV,
                                                           M1, bm1, M2, bm2, out_s, out_v);
}